// Round 7
// baseline (143.286 us; speedup 1.0000x reference)
//
#include <hip/hip_runtime.h>
#include <hip/hip_bf16.h>

#define N_NODES 40000
#define N_EDGES 640000

typedef __attribute__((ext_vector_type(8))) short bfrag;   // 8 bf16
typedef __attribute__((ext_vector_type(4))) float ffrag;   // 4 fp32 acc
typedef __attribute__((ext_vector_type(4))) unsigned u32x4; // native 16B vec
                                                            // (nontemporal builtin
                                                            // rejects HIP_vector_type)

__device__ __forceinline__ float b2f_lo(unsigned u) {
    return __builtin_bit_cast(float, u << 16);
}
__device__ __forceinline__ float b2f_hi(unsigned u) {
    return __builtin_bit_cast(float, u & 0xffff0000u);
}
__device__ __forceinline__ unsigned short f2b(float f) {
    return __builtin_bit_cast(unsigned short, __float2bfloat16(f));
}

// ---------------- prepW: weight chain only (32 blocks, ~3us) ----------------
__global__ __launch_bounds__(256) void prepW(const float* __restrict__ W1,
                                             const float* __restrict__ W2,
                                             const float* __restrict__ W3,
                                             unsigned short* __restrict__ Wt123) {
    __shared__ float uS[4][128];
    const int wv   = threadIdx.x >> 6;
    const int lane = threadIdx.x & 63;
    const int k    = blockIdx.x * 4 + wv;   // 0..127

    float u0 = 0.f, u1 = 0.f;
    const float* w1p = W1 + k * 128;
    const float* w2p = W2 + 2 * lane;
#pragma unroll 8
    for (int j = 0; j < 128; j++) {
        float a  = w1p[j];
        float2 w = *(const float2*)(w2p + (size_t)j * 128);
        u0 += a * w.x;
        u1 += a * w.y;
    }
    uS[wv][2 * lane]     = u0;
    uS[wv][2 * lane + 1] = u1;
    __syncthreads();

    float acc = 0.f;
    const float* w3p = W3 + lane;
#pragma unroll 8
    for (int l = 0; l < 128; l++)
        acc += uS[wv][l] * w3p[(size_t)l * 64];
    Wt123[lane * 128 + k] = f2b(acc);
}

// ------- gemmR: MFMA GEMM (blocks 0..624) + rowptr (blocks 625..1406) -------
#define GEMM_BLOCKS 625
#define RP_BLOCKS   782     // ceil((640000/4 + 40001)/256)
__global__ __launch_bounds__(256) void gemmR(const float* __restrict__ X,
                                             const unsigned short* __restrict__ Wt,
                                             unsigned short* __restrict__ Y,
                                             const int* __restrict__ dst,
                                             int* __restrict__ rowptr) {
    const int bid = blockIdx.x;
    if (bid >= GEMM_BLOCKS) {
        // ---- rowptr via int4 adjacent-diff ----
        int i = (bid - GEMM_BLOCKS) * 256 + threadIdx.x;
        if (i < N_EDGES / 4) {
            int e = i * 4;
            int4 d4 = *(const int4*)(dst + e);
            int dp = (e == 0) ? -1 : dst[e - 1];
            for (int n = dp + 1;   n <= d4.x; n++) rowptr[n] = e;
            for (int n = d4.x + 1; n <= d4.y; n++) rowptr[n] = e + 1;
            for (int n = d4.y + 1; n <= d4.z; n++) rowptr[n] = e + 2;
            for (int n = d4.z + 1; n <= d4.w; n++) rowptr[n] = e + 3;
        } else if (i < N_EDGES / 4 + N_NODES + 1) {
            int n = i - N_EDGES / 4;           // 0..N_NODES
            if (n > dst[N_EDGES - 1]) rowptr[n] = N_EDGES;
        }
        return;
    }

    // ---- MFMA GEMM: T[N,64] = bf16( X[N,128] @ W123 ), 64 rows/block ----
    const int wv   = threadIdx.x >> 6;
    const int lane = threadIdx.x & 63;
    const int ml   = lane & 15;
    const int quad = lane >> 4;
    const int row0 = bid * 64 + wv * 16;

    ffrag acc[4];
#pragma unroll
    for (int c = 0; c < 4; c++) acc[c] = (ffrag)0.f;

#pragma unroll
    for (int kb = 0; kb < 128; kb += 32) {
        const float* p = X + (size_t)(row0 + ml) * 128 + kb + quad * 8;
        float4 u0 = *(const float4*)p;
        float4 u1 = *(const float4*)(p + 4);
        bfrag a;
        a[0] = (short)f2b(u0.x); a[1] = (short)f2b(u0.y);
        a[2] = (short)f2b(u0.z); a[3] = (short)f2b(u0.w);
        a[4] = (short)f2b(u1.x); a[5] = (short)f2b(u1.y);
        a[6] = (short)f2b(u1.z); a[7] = (short)f2b(u1.w);
#pragma unroll
        for (int c = 0; c < 4; c++) {
            const int col = c * 16 + ml;
            bfrag b = *(const bfrag*)(Wt + (size_t)col * 128 + kb + quad * 8);
            acc[c] = __builtin_amdgcn_mfma_f32_16x16x32_bf16(a, b, acc[c], 0, 0, 0);
        }
    }
#pragma unroll
    for (int c = 0; c < 4; c++)
#pragma unroll
        for (int i = 0; i < 4; i++)
            Y[(size_t)(row0 + quad * 4 + i) * 64 + c * 16 + ml] = f2b(acc[c][i]);
}

// ---------------- CSR scatter, D=64, bf16 in — R18b: L1-bypass gathers ------
// Schedule levers exhausted (R12/R13/R15/R16/R17 ledger): scatter is ~36 cy
// per random 128B line per CU — hypothesis: L1/TCP miss path (finite MSHR
// fill slots). Random gathers over 5.1MB table: ~0% L1 hit, so L1 allocation
// is pure overhead. Nontemporal load = no-L1-allocate policy; requests ride
// the 64-deep per-wave vmcnt queue to L2. srcE/rowptr/stores keep default
// caching. If neutral -> request-path floor -> ROOFLINE.
#define IDX_LDS 2048
template<bool OUT_F32>
__global__ __launch_bounds__(256) void scatter8(const unsigned short* __restrict__ T,
                                                const int* __restrict__ srcE,
                                                const int* __restrict__ rowptr,
                                                void* __restrict__ Hv) {
    __shared__ int shIdx[IDX_LDS];
    const int tid   = threadIdx.x;
    const int node0 = blockIdx.x * 32;
    const int ebase = rowptr[node0];
    const int etop  = rowptr[node0 + 32];
    const int total = etop - ebase;

    const int lim = total < IDX_LDS ? total : IDX_LDS;
    for (int j = tid; j < lim; j += 256) shIdx[j] = srcE[ebase + j];
    __syncthreads();

    const int lane = tid & 63;
    const int g    = lane >> 3;          // group 0..7 -> node
    const int c8   = (lane & 7) * 8;     // cols c8..c8+7
    const int node = node0 + (tid >> 6) * 8 + g;
    const int e0 = rowptr[node], e1 = rowptr[node + 1];

    float a0 = 0.f, a1 = 0.f, a2 = 0.f, a3 = 0.f;
    float a4 = 0.f, a5 = 0.f, a6 = 0.f, a7 = 0.f;

#define GATH(s) (__builtin_nontemporal_load((const u32x4*)(T + (size_t)(s) * 64 + c8)))
#define ACCQ(t0, t1, t2, t3)                                                  \
    do {                                                                      \
        a0 += (b2f_lo(t0.x) + b2f_lo(t1.x)) + (b2f_lo(t2.x) + b2f_lo(t3.x));  \
        a1 += (b2f_hi(t0.x) + b2f_hi(t1.x)) + (b2f_hi(t2.x) + b2f_hi(t3.x));  \
        a2 += (b2f_lo(t0.y) + b2f_lo(t1.y)) + (b2f_lo(t2.y) + b2f_lo(t3.y));  \
        a3 += (b2f_hi(t0.y) + b2f_hi(t1.y)) + (b2f_hi(t2.y) + b2f_hi(t3.y));  \
        a4 += (b2f_lo(t0.z) + b2f_lo(t1.z)) + (b2f_lo(t2.z) + b2f_lo(t3.z));  \
        a5 += (b2f_hi(t0.z) + b2f_hi(t1.z)) + (b2f_hi(t2.z) + b2f_hi(t3.z));  \
        a6 += (b2f_lo(t0.w) + b2f_lo(t1.w)) + (b2f_lo(t2.w) + b2f_lo(t3.w));  \
        a7 += (b2f_hi(t0.w) + b2f_hi(t1.w)) + (b2f_hi(t2.w) + b2f_hi(t3.w));  \
    } while (0)

    int e = e0;
    if (total <= IDX_LDS) {
        // ---- fast path: indices from LDS, depth-2 gather pipeline ----
        u32x4 A0, A1, A2, A3, B0, B1, B2, B3;
        bool haveA = false, haveB = false;
        if (e + 4 <= e1) {
            int o = e - ebase;
            A0 = GATH(shIdx[o]);     A1 = GATH(shIdx[o + 1]);
            A2 = GATH(shIdx[o + 2]); A3 = GATH(shIdx[o + 3]);
            e += 4; haveA = true;
            if (e + 4 <= e1) {
                o = e - ebase;
                B0 = GATH(shIdx[o]);     B1 = GATH(shIdx[o + 1]);
                B2 = GATH(shIdx[o + 2]); B3 = GATH(shIdx[o + 3]);
                e += 4; haveB = true;
            }
        }
        while (haveA) {
            ACCQ(A0, A1, A2, A3);
            if (e + 4 <= e1) {
                int o = e - ebase;
                A0 = GATH(shIdx[o]);     A1 = GATH(shIdx[o + 1]);
                A2 = GATH(shIdx[o + 2]); A3 = GATH(shIdx[o + 3]);
                e += 4;
            } else haveA = false;
            if (!haveB) break;
            ACCQ(B0, B1, B2, B3);
            if (e + 4 <= e1) {
                int o = e - ebase;
                B0 = GATH(shIdx[o]);     B1 = GATH(shIdx[o + 1]);
                B2 = GATH(shIdx[o + 2]); B3 = GATH(shIdx[o + 3]);
                e += 4;
            } else haveB = false;
        }
        // tail 0..3 edges, batched single round trip
        const int rem = e1 - e;
        if (rem > 0) {
            int o = e - ebase;
            int s0 = shIdx[o];
            int s1 = (rem > 1) ? shIdx[o + 1] : s0;
            int s2 = (rem > 2) ? shIdx[o + 2] : s0;
            u32x4 q0 = GATH(s0), q1 = GATH(s1), q2 = GATH(s2);
            a0 += b2f_lo(q0.x); a1 += b2f_hi(q0.x);
            a2 += b2f_lo(q0.y); a3 += b2f_hi(q0.y);
            a4 += b2f_lo(q0.z); a5 += b2f_hi(q0.z);
            a6 += b2f_lo(q0.w); a7 += b2f_hi(q0.w);
            if (rem > 1) {
                a0 += b2f_lo(q1.x); a1 += b2f_hi(q1.x);
                a2 += b2f_lo(q1.y); a3 += b2f_hi(q1.y);
                a4 += b2f_lo(q1.z); a5 += b2f_hi(q1.z);
                a6 += b2f_lo(q1.w); a7 += b2f_hi(q1.w);
            }
            if (rem > 2) {
                a0 += b2f_lo(q2.x); a1 += b2f_hi(q2.x);
                a2 += b2f_lo(q2.y); a3 += b2f_hi(q2.y);
                a4 += b2f_lo(q2.z); a5 += b2f_hi(q2.z);
                a6 += b2f_lo(q2.w); a7 += b2f_hi(q2.w);
            }
        }
    } else {
        // ---- overflow fallback (statistically unreachable): R15 loop ----
        u32x4 t0, t1, t2, t3;
        bool have = (e + 4 <= e1);
        if (have) {
            int s0 = srcE[e], s1 = srcE[e + 1], s2 = srcE[e + 2], s3 = srcE[e + 3];
            t0 = GATH(s0); t1 = GATH(s1); t2 = GATH(s2); t3 = GATH(s3);
            e += 4;
        }
        while (have) {
            const bool next = (e + 4 <= e1);
            int s0, s1, s2, s3;
            if (next) { s0 = srcE[e]; s1 = srcE[e + 1]; s2 = srcE[e + 2]; s3 = srcE[e + 3]; }
            ACCQ(t0, t1, t2, t3);
            if (next) {
                t0 = GATH(s0); t1 = GATH(s1); t2 = GATH(s2); t3 = GATH(s3);
                e += 4;
            }
            have = next;
        }
        const int rem = e1 - e;
        if (rem > 0) {
            int s0 = srcE[e];
            int s1 = (rem > 1) ? srcE[e + 1] : s0;
            int s2 = (rem > 2) ? srcE[e + 2] : s0;
            u32x4 q0 = GATH(s0), q1 = GATH(s1), q2 = GATH(s2);
            a0 += b2f_lo(q0.x); a1 += b2f_hi(q0.x);
            a2 += b2f_lo(q0.y); a3 += b2f_hi(q0.y);
            a4 += b2f_lo(q0.z); a5 += b2f_hi(q0.z);
            a6 += b2f_lo(q0.w); a7 += b2f_hi(q0.w);
            if (rem > 1) {
                a0 += b2f_lo(q1.x); a1 += b2f_hi(q1.x);
                a2 += b2f_lo(q1.y); a3 += b2f_hi(q1.y);
                a4 += b2f_lo(q1.z); a5 += b2f_hi(q1.z);
                a6 += b2f_lo(q1.w); a7 += b2f_hi(q1.w);
            }
            if (rem > 2) {
                a0 += b2f_lo(q2.x); a1 += b2f_hi(q2.x);
                a2 += b2f_lo(q2.y); a3 += b2f_hi(q2.y);
                a4 += b2f_lo(q2.z); a5 += b2f_hi(q2.z);
                a6 += b2f_lo(q2.w); a7 += b2f_hi(q2.w);
            }
        }
    }
#undef GATH
#undef ACCQ

    if constexpr (OUT_F32) {
        float* q = (float*)Hv + (size_t)node * 64 + c8;
        *(float4*)q       = make_float4(a0, a1, a2, a3);
        *(float4*)(q + 4) = make_float4(a4, a5, a6, a7);
    } else {
        ushort4 o0, o1;
        o0.x = f2b(a0); o0.y = f2b(a1); o0.z = f2b(a2); o0.w = f2b(a3);
        o1.x = f2b(a4); o1.y = f2b(a5); o1.z = f2b(a6); o1.w = f2b(a7);
        unsigned short* q = (unsigned short*)Hv + (size_t)node * 64 + c8;
        *(ushort4*)q       = o0;
        *(ushort4*)(q + 4) = o1;
    }
}

extern "C" void kernel_launch(void* const* d_in, const int* in_sizes, int n_in,
                              void* d_out, int out_size, void* d_ws, size_t ws_size,
                              hipStream_t stream) {
    const int*   src  = (const int*)d_in[0];
    const int*   dst  = (const int*)d_in[1];
    const float* feat = (const float*)d_in[2];
    const float* W1   = (const float*)d_in[3];
    const float* W2   = (const float*)d_in[4];
    const float* W3   = (const float*)d_in[5];
    float* out = (float*)d_out;

    // ws layout (bytes): T@0, H@5.25M, rowptr@10.5M, Wt123 after.
    char* wsb = (char*)d_ws;
    unsigned short* T     = (unsigned short*)wsb;
    unsigned short* H     = (unsigned short*)(wsb + (size_t)5505024);
    int* rowptr           = (int*)(wsb + (size_t)11010048);
    unsigned short* Wt123 = (unsigned short*)(wsb + (size_t)11010048 + 163968);

    const int scatterBlocks = (N_NODES + 31) / 32;   // 1250 (8 nodes x 4 waves)

    // out = S^3 . (X @ (W1 W2 W3))  — S = segment-sum, commutes with W
    prepW<<<32, 256, 0, stream>>>(W1, W2, W3, Wt123);
    gemmR<<<GEMM_BLOCKS + RP_BLOCKS, 256, 0, stream>>>(feat, Wt123, T, dst, rowptr);
    scatter8<false><<<scatterBlocks, 256, 0, stream>>>(T, src, rowptr, H);
    scatter8<false><<<scatterBlocks, 256, 0, stream>>>(H, src, rowptr, T);
    scatter8<true><<<scatterBlocks, 256, 0, stream>>>(T, src, rowptr, out);
}

// Round 8
// 135.354 us; speedup vs baseline: 1.0586x; 1.0586x over previous
//
#include <hip/hip_runtime.h>
#include <hip/hip_bf16.h>

#define N_NODES 40000
#define N_EDGES 640000

typedef __attribute__((ext_vector_type(8))) short bfrag;   // 8 bf16
typedef __attribute__((ext_vector_type(4))) float ffrag;   // 4 fp32 acc

__device__ __forceinline__ float b2f_lo(unsigned u) {
    return __builtin_bit_cast(float, u << 16);
}
__device__ __forceinline__ float b2f_hi(unsigned u) {
    return __builtin_bit_cast(float, u & 0xffff0000u);
}
__device__ __forceinline__ unsigned short f2b(float f) {
    return __builtin_bit_cast(unsigned short, __float2bfloat16(f));
}

// ---------------- prepW: weight chain only (32 blocks, ~3us) ----------------
__global__ __launch_bounds__(256) void prepW(const float* __restrict__ W1,
                                             const float* __restrict__ W2,
                                             const float* __restrict__ W3,
                                             unsigned short* __restrict__ Wt123) {
    __shared__ float uS[4][128];
    const int wv   = threadIdx.x >> 6;
    const int lane = threadIdx.x & 63;
    const int k    = blockIdx.x * 4 + wv;   // 0..127

    float u0 = 0.f, u1 = 0.f;
    const float* w1p = W1 + k * 128;
    const float* w2p = W2 + 2 * lane;
#pragma unroll 8
    for (int j = 0; j < 128; j++) {
        float a  = w1p[j];
        float2 w = *(const float2*)(w2p + (size_t)j * 128);
        u0 += a * w.x;
        u1 += a * w.y;
    }
    uS[wv][2 * lane]     = u0;
    uS[wv][2 * lane + 1] = u1;
    __syncthreads();

    float acc = 0.f;
    const float* w3p = W3 + lane;
#pragma unroll 8
    for (int l = 0; l < 128; l++)
        acc += uS[wv][l] * w3p[(size_t)l * 64];
    Wt123[lane * 128 + k] = f2b(acc);
}

// ------- gemmR: MFMA GEMM (blocks 0..624) + rowptr (blocks 625..1406) -------
// R19: T output now COLUMN-SPLIT: T_lo[40000][32] cols 0-31, T_hi cols 32-63
// (2.56 MB each — the point: each half fits a 4 MB per-XCD L2).
#define GEMM_BLOCKS 625
#define RP_BLOCKS   782     // ceil((640000/4 + 40001)/256)
__global__ __launch_bounds__(256) void gemmR(const float* __restrict__ X,
                                             const unsigned short* __restrict__ Wt,
                                             unsigned short* __restrict__ Ylo,
                                             unsigned short* __restrict__ Yhi,
                                             const int* __restrict__ dst,
                                             int* __restrict__ rowptr) {
    const int bid = blockIdx.x;
    if (bid >= GEMM_BLOCKS) {
        // ---- rowptr via int4 adjacent-diff ----
        int i = (bid - GEMM_BLOCKS) * 256 + threadIdx.x;
        if (i < N_EDGES / 4) {
            int e = i * 4;
            int4 d4 = *(const int4*)(dst + e);
            int dp = (e == 0) ? -1 : dst[e - 1];
            for (int n = dp + 1;   n <= d4.x; n++) rowptr[n] = e;
            for (int n = d4.x + 1; n <= d4.y; n++) rowptr[n] = e + 1;
            for (int n = d4.y + 1; n <= d4.z; n++) rowptr[n] = e + 2;
            for (int n = d4.z + 1; n <= d4.w; n++) rowptr[n] = e + 3;
        } else if (i < N_EDGES / 4 + N_NODES + 1) {
            int n = i - N_EDGES / 4;           // 0..N_NODES
            if (n > dst[N_EDGES - 1]) rowptr[n] = N_EDGES;
        }
        return;
    }

    // ---- MFMA GEMM: T[N,64] = bf16( X[N,128] @ W123 ), 64 rows/block ----
    const int wv   = threadIdx.x >> 6;
    const int lane = threadIdx.x & 63;
    const int ml   = lane & 15;
    const int quad = lane >> 4;
    const int row0 = bid * 64 + wv * 16;

    ffrag acc[4];
#pragma unroll
    for (int c = 0; c < 4; c++) acc[c] = (ffrag)0.f;

#pragma unroll
    for (int kb = 0; kb < 128; kb += 32) {
        const float* p = X + (size_t)(row0 + ml) * 128 + kb + quad * 8;
        float4 u0 = *(const float4*)p;
        float4 u1 = *(const float4*)(p + 4);
        bfrag a;
        a[0] = (short)f2b(u0.x); a[1] = (short)f2b(u0.y);
        a[2] = (short)f2b(u0.z); a[3] = (short)f2b(u0.w);
        a[4] = (short)f2b(u1.x); a[5] = (short)f2b(u1.y);
        a[6] = (short)f2b(u1.z); a[7] = (short)f2b(u1.w);
#pragma unroll
        for (int c = 0; c < 4; c++) {
            const int col = c * 16 + ml;
            bfrag b = *(const bfrag*)(Wt + (size_t)col * 128 + kb + quad * 8);
            acc[c] = __builtin_amdgcn_mfma_f32_16x16x32_bf16(a, b, acc[c], 0, 0, 0);
        }
    }
#pragma unroll
    for (int c = 0; c < 4; c++) {
        unsigned short* Yh = (c >= 2) ? Yhi : Ylo;
#pragma unroll
        for (int i = 0; i < 4; i++)
            Yh[(size_t)(row0 + quad * 4 + i) * 32 + (c & 1) * 16 + ml] = f2b(acc[c][i]);
    }
}

// -------- CSR scatter, R19: column-split halves + XCD-partitioned L2 --------
// Evidence: all wave-side levers null/neg (R12/13/15/16/17); R18 L1-bypass
// HURT (+10us) -> cache retention is real (deg-16 row reuse). Remaining lever:
// footprint. T (5.12MB) > 4MB per-XCD L2 -> every XCD thrashes to L3. Split
// columns: T_lo/T_hi 2.56MB each; bid&7 routes XCDs 0-3 -> lo chain, 4-7 ->
// hi chain (round-robin heuristic, correctness-neutral). Each XCD's L2 holds
// only its 2.56MB half -> near-full L2 hit. Cost: 2 x 64B requests per edge
// (vs 1 x 128B); R13 priced that at ~+3us/scatter. 16 nodes/wave (4-lane
// groups), 64 nodes/block, depth-2 pipeline + LDS-staged indices retained.
#define HIDX 4096
template<bool OUT_F32>
__global__ __launch_bounds__(256) void scatterS(const unsigned short* __restrict__ Tlo,
                                                const unsigned short* __restrict__ Thi,
                                                const int* __restrict__ srcE,
                                                const int* __restrict__ rowptr,
                                                void* __restrict__ Dlo,
                                                void* __restrict__ Dhi) {
    __shared__ int shIdx[HIDX];
    const int bid   = blockIdx.x;
    const int xcd   = bid & 7;
    const int h     = xcd >> 2;                       // 0 = cols 0-31, 1 = 32-63
    const int chunk = (bid >> 3) * 4 + (xcd & 3);     // 0..639
    if (chunk >= 625) return;
    const unsigned short* T = h ? Thi : Tlo;

    const int tid   = threadIdx.x;
    const int node0 = chunk * 64;
    const int ebase = rowptr[node0];
    const int etop  = rowptr[node0 + 64];
    const int total = etop - ebase;

    const int lim = total < HIDX ? total : HIDX;
    for (int j = tid; j < lim; j += 256) shIdx[j] = srcE[ebase + j];
    __syncthreads();

    const int lane = tid & 63;
    const int g    = lane >> 2;          // group 0..15 -> node
    const int c8   = (lane & 3) * 8;     // 8 bf16 cols within the half
    const int node = node0 + (tid >> 6) * 16 + g;
    const int e0 = rowptr[node], e1 = rowptr[node + 1];

    float a0 = 0.f, a1 = 0.f, a2 = 0.f, a3 = 0.f;
    float a4 = 0.f, a5 = 0.f, a6 = 0.f, a7 = 0.f;

#define GATH(s) (*(const uint4*)(T + (size_t)(s) * 32 + c8))
#define ACCQ(t0, t1, t2, t3)                                                  \
    do {                                                                      \
        a0 += (b2f_lo(t0.x) + b2f_lo(t1.x)) + (b2f_lo(t2.x) + b2f_lo(t3.x));  \
        a1 += (b2f_hi(t0.x) + b2f_hi(t1.x)) + (b2f_hi(t2.x) + b2f_hi(t3.x));  \
        a2 += (b2f_lo(t0.y) + b2f_lo(t1.y)) + (b2f_lo(t2.y) + b2f_lo(t3.y));  \
        a3 += (b2f_hi(t0.y) + b2f_hi(t1.y)) + (b2f_hi(t2.y) + b2f_hi(t3.y));  \
        a4 += (b2f_lo(t0.z) + b2f_lo(t1.z)) + (b2f_lo(t2.z) + b2f_lo(t3.z));  \
        a5 += (b2f_hi(t0.z) + b2f_hi(t1.z)) + (b2f_hi(t2.z) + b2f_hi(t3.z));  \
        a6 += (b2f_lo(t0.w) + b2f_lo(t1.w)) + (b2f_lo(t2.w) + b2f_lo(t3.w));  \
        a7 += (b2f_hi(t0.w) + b2f_hi(t1.w)) + (b2f_hi(t2.w) + b2f_hi(t3.w));  \
    } while (0)

    int e = e0;
    if (total <= HIDX) {
        // ---- fast path: indices from LDS, depth-2 gather pipeline ----
        uint4 A0, A1, A2, A3, B0, B1, B2, B3;
        bool haveA = false, haveB = false;
        if (e + 4 <= e1) {
            int o = e - ebase;
            A0 = GATH(shIdx[o]);     A1 = GATH(shIdx[o + 1]);
            A2 = GATH(shIdx[o + 2]); A3 = GATH(shIdx[o + 3]);
            e += 4; haveA = true;
            if (e + 4 <= e1) {
                o = e - ebase;
                B0 = GATH(shIdx[o]);     B1 = GATH(shIdx[o + 1]);
                B2 = GATH(shIdx[o + 2]); B3 = GATH(shIdx[o + 3]);
                e += 4; haveB = true;
            }
        }
        while (haveA) {
            ACCQ(A0, A1, A2, A3);
            if (e + 4 <= e1) {
                int o = e - ebase;
                A0 = GATH(shIdx[o]);     A1 = GATH(shIdx[o + 1]);
                A2 = GATH(shIdx[o + 2]); A3 = GATH(shIdx[o + 3]);
                e += 4;
            } else haveA = false;
            if (!haveB) break;
            ACCQ(B0, B1, B2, B3);
            if (e + 4 <= e1) {
                int o = e - ebase;
                B0 = GATH(shIdx[o]);     B1 = GATH(shIdx[o + 1]);
                B2 = GATH(shIdx[o + 2]); B3 = GATH(shIdx[o + 3]);
                e += 4;
            } else haveB = false;
        }
        // tail 0..3 edges, batched single round trip
        const int rem = e1 - e;
        if (rem > 0) {
            int o = e - ebase;
            int s0 = shIdx[o];
            int s1 = (rem > 1) ? shIdx[o + 1] : s0;
            int s2 = (rem > 2) ? shIdx[o + 2] : s0;
            uint4 q0 = GATH(s0), q1 = GATH(s1), q2 = GATH(s2);
            a0 += b2f_lo(q0.x); a1 += b2f_hi(q0.x);
            a2 += b2f_lo(q0.y); a3 += b2f_hi(q0.y);
            a4 += b2f_lo(q0.z); a5 += b2f_hi(q0.z);
            a6 += b2f_lo(q0.w); a7 += b2f_hi(q0.w);
            if (rem > 1) {
                a0 += b2f_lo(q1.x); a1 += b2f_hi(q1.x);
                a2 += b2f_lo(q1.y); a3 += b2f_hi(q1.y);
                a4 += b2f_lo(q1.z); a5 += b2f_hi(q1.z);
                a6 += b2f_lo(q1.w); a7 += b2f_hi(q1.w);
            }
            if (rem > 2) {
                a0 += b2f_lo(q2.x); a1 += b2f_hi(q2.x);
                a2 += b2f_lo(q2.y); a3 += b2f_hi(q2.y);
                a4 += b2f_lo(q2.z); a5 += b2f_hi(q2.z);
                a6 += b2f_lo(q2.w); a7 += b2f_hi(q2.w);
            }
        }
    } else {
        // ---- overflow fallback (statistically unreachable): per-edge ----
        for (int ee = e0; ee < e1; ee++) {
            uint4 t0 = GATH(srcE[ee]);
            a0 += b2f_lo(t0.x); a1 += b2f_hi(t0.x);
            a2 += b2f_lo(t0.y); a3 += b2f_hi(t0.y);
            a4 += b2f_lo(t0.z); a5 += b2f_hi(t0.z);
            a6 += b2f_lo(t0.w); a7 += b2f_hi(t0.w);
        }
    }
#undef GATH
#undef ACCQ

    if constexpr (OUT_F32) {
        // Dlo == Dhi == out (f32 [N][64]); h picks the column half
        float* q = (float*)Dlo + (size_t)node * 64 + h * 32 + (lane & 3) * 8;
        *(float4*)q       = make_float4(a0, a1, a2, a3);
        *(float4*)(q + 4) = make_float4(a4, a5, a6, a7);
    } else {
        ushort4 o0, o1;
        o0.x = f2b(a0); o0.y = f2b(a1); o0.z = f2b(a2); o0.w = f2b(a3);
        o1.x = f2b(a4); o1.y = f2b(a5); o1.z = f2b(a6); o1.w = f2b(a7);
        unsigned short* q = (unsigned short*)(h ? Dhi : Dlo)
                          + (size_t)node * 32 + (lane & 3) * 8;
        *(ushort4*)q       = o0;
        *(ushort4*)(q + 4) = o1;
    }
}

extern "C" void kernel_launch(void* const* d_in, const int* in_sizes, int n_in,
                              void* d_out, int out_size, void* d_ws, size_t ws_size,
                              hipStream_t stream) {
    const int*   src  = (const int*)d_in[0];
    const int*   dst  = (const int*)d_in[1];
    const float* feat = (const float*)d_in[2];
    const float* W1   = (const float*)d_in[3];
    const float* W2   = (const float*)d_in[4];
    const float* W3   = (const float*)d_in[5];
    float* out = (float*)d_out;

    // ws layout (bytes): Tlo@0, Thi@2.56M, Hlo@5.12M, Hhi@7.68M, rowptr@10.24M,
    // Wt123 after. Each half table = 40000*32*2B = 2,560,000 B.
    char* wsb = (char*)d_ws;
    unsigned short* Tlo   = (unsigned short*)wsb;
    unsigned short* Thi   = (unsigned short*)(wsb + (size_t)2560000);
    unsigned short* Hlo   = (unsigned short*)(wsb + (size_t)5120000);
    unsigned short* Hhi   = (unsigned short*)(wsb + (size_t)7680000);
    int* rowptr           = (int*)(wsb + (size_t)10240000);
    unsigned short* Wt123 = (unsigned short*)(wsb + (size_t)10240000 + 160016);

    const int scatterBlocks = 1280;   // 2 halves x 640 chunks (64 nodes each)

    // out = S^3 . (X @ (W1 W2 W3)) — S = segment-sum, commutes with W;
    // S acts per-column -> lo/hi chains fully independent.
    prepW<<<32, 256, 0, stream>>>(W1, W2, W3, Wt123);
    gemmR<<<GEMM_BLOCKS + RP_BLOCKS, 256, 0, stream>>>(feat, Wt123, Tlo, Thi, dst, rowptr);
    scatterS<false><<<scatterBlocks, 256, 0, stream>>>(Tlo, Thi, src, rowptr, Hlo, Hhi);
    scatterS<false><<<scatterBlocks, 256, 0, stream>>>(Hlo, Hhi, src, rowptr, Tlo, Thi);
    scatterS<true><<<scatterBlocks, 256, 0, stream>>>(Tlo, Thi, src, rowptr, out, out);
}

// Round 9
// 133.308 us; speedup vs baseline: 1.0748x; 1.0153x over previous
//
#include <hip/hip_runtime.h>
#include <hip/hip_bf16.h>

#define N_NODES 40000
#define N_EDGES 640000

typedef __attribute__((ext_vector_type(8))) short bfrag;   // 8 bf16
typedef __attribute__((ext_vector_type(4))) float ffrag;   // 4 fp32 acc

__device__ __forceinline__ float b2f_lo(unsigned u) {
    return __builtin_bit_cast(float, u << 16);
}
__device__ __forceinline__ float b2f_hi(unsigned u) {
    return __builtin_bit_cast(float, u & 0xffff0000u);
}
__device__ __forceinline__ unsigned short f2b(float f) {
    return __builtin_bit_cast(unsigned short, __float2bfloat16(f));
}

// ---------------- prep: rowptr (int4 adjacent-diff) + Wt123 (k-parallel) ----
// FINAL (R20 = R16 restored, session best 133.6us). Full ledger in session
// notes: R12 edge-split +, R13 col-split +10, R14 grid.sync +495, R15 depth-1
// -3, R16 LDS-idx+depth-2 -0.7 (best), R17 chain-split +0.8, R18 nt-loads
// +9.7, R19 L2-footprint-partition +1.0. Scatter floor = 1.92M random 128B
// line-requests; locality gain == request-count loss (R19), cache retention
// already load-bearing (R18), TLP/ILP saturated (R13/15/16).
#define RP_BLOCKS 782     // ceil((640000/4 + 40001)/256)
#define W_BLOCKS  32
__global__ __launch_bounds__(256) void prep(const int* __restrict__ dst,
                                            int* __restrict__ rowptr,
                                            const float* __restrict__ W1,
                                            const float* __restrict__ W2,
                                            const float* __restrict__ W3,
                                            unsigned short* __restrict__ Wt123) {
    __shared__ float uS[4][128];
    const int bid = blockIdx.x;
    if (bid < RP_BLOCKS) {
        int i = bid * 256 + threadIdx.x;
        if (i < N_EDGES / 4) {
            int e = i * 4;
            int4 d4 = *(const int4*)(dst + e);
            int dp = (e == 0) ? -1 : dst[e - 1];
            for (int n = dp + 1;   n <= d4.x; n++) rowptr[n] = e;
            for (int n = d4.x + 1; n <= d4.y; n++) rowptr[n] = e + 1;
            for (int n = d4.y + 1; n <= d4.z; n++) rowptr[n] = e + 2;
            for (int n = d4.z + 1; n <= d4.w; n++) rowptr[n] = e + 3;
        } else if (i < N_EDGES / 4 + N_NODES + 1) {
            int n = i - N_EDGES / 4;           // 0..N_NODES
            if (n > dst[N_EDGES - 1]) rowptr[n] = N_EDGES;
        }
        return;
    }

    // weight chain: one wave per k (128 waves) — latency hidden by TLP
    const int wv   = threadIdx.x >> 6;
    const int lane = threadIdx.x & 63;
    const int k    = (bid - RP_BLOCKS) * 4 + wv;   // 0..127

    float u0 = 0.f, u1 = 0.f;
    const float* w1p = W1 + k * 128;
    const float* w2p = W2 + 2 * lane;
#pragma unroll 8
    for (int j = 0; j < 128; j++) {
        float a  = w1p[j];
        float2 w = *(const float2*)(w2p + (size_t)j * 128);
        u0 += a * w.x;
        u1 += a * w.y;
    }
    uS[wv][2 * lane]     = u0;
    uS[wv][2 * lane + 1] = u1;
    __syncthreads();

    float acc = 0.f;
    const float* w3p = W3 + lane;
#pragma unroll 8
    for (int l = 0; l < 128; l++)
        acc += uS[wv][l] * w3p[(size_t)l * 64];
    Wt123[lane * 128 + k] = f2b(acc);
}

// ---------------- MFMA GEMM: T[N,64] = bf16( X[N,128] @ W123 ) ----------------
__global__ __launch_bounds__(256) void gemm_mfma64(const float* __restrict__ X,
                                                   const unsigned short* __restrict__ Wt,
                                                   unsigned short* __restrict__ Y) {
    const int wv   = threadIdx.x >> 6;
    const int lane = threadIdx.x & 63;
    const int ml   = lane & 15;
    const int quad = lane >> 4;
    const int row0 = blockIdx.x * 64 + wv * 16;

    ffrag acc[4];
#pragma unroll
    for (int c = 0; c < 4; c++) acc[c] = (ffrag)0.f;

#pragma unroll
    for (int kb = 0; kb < 128; kb += 32) {
        const float* p = X + (size_t)(row0 + ml) * 128 + kb + quad * 8;
        float4 u0 = *(const float4*)p;
        float4 u1 = *(const float4*)(p + 4);
        bfrag a;
        a[0] = (short)f2b(u0.x); a[1] = (short)f2b(u0.y);
        a[2] = (short)f2b(u0.z); a[3] = (short)f2b(u0.w);
        a[4] = (short)f2b(u1.x); a[5] = (short)f2b(u1.y);
        a[6] = (short)f2b(u1.z); a[7] = (short)f2b(u1.w);
#pragma unroll
        for (int c = 0; c < 4; c++) {
            const int col = c * 16 + ml;
            bfrag b = *(const bfrag*)(Wt + (size_t)col * 128 + kb + quad * 8);
            acc[c] = __builtin_amdgcn_mfma_f32_16x16x32_bf16(a, b, acc[c], 0, 0, 0);
        }
    }
#pragma unroll
    for (int c = 0; c < 4; c++)
#pragma unroll
        for (int i = 0; i < 4; i++)
            Y[(size_t)(row0 + quad * 4 + i) * 64 + c * 16 + ml] = f2b(acc[c][i]);
}

// ---------------- CSR scatter, D=64, bf16 in — R16 config (session best) ----
// 8 nodes/wave (8-lane groups), lane owns 8 cols via one 16B uint4 =
// exactly one aligned 128B line per edge per gather instr (minimal).
// Indices LDS-staged (coalesced, no in-loop srcE round trip); gathers
// depth-2 pipelined in named regs.
#define IDX_LDS 2048
template<bool OUT_F32>
__global__ __launch_bounds__(256) void scatter8(const unsigned short* __restrict__ T,
                                                const int* __restrict__ srcE,
                                                const int* __restrict__ rowptr,
                                                void* __restrict__ Hv) {
    __shared__ int shIdx[IDX_LDS];
    const int tid   = threadIdx.x;
    const int node0 = blockIdx.x * 32;
    const int ebase = rowptr[node0];
    const int etop  = rowptr[node0 + 32];
    const int total = etop - ebase;

    const int lim = total < IDX_LDS ? total : IDX_LDS;
    for (int j = tid; j < lim; j += 256) shIdx[j] = srcE[ebase + j];
    __syncthreads();

    const int lane = tid & 63;
    const int g    = lane >> 3;          // group 0..7 -> node
    const int c8   = (lane & 7) * 8;     // cols c8..c8+7
    const int node = node0 + (tid >> 6) * 8 + g;
    const int e0 = rowptr[node], e1 = rowptr[node + 1];

    float a0 = 0.f, a1 = 0.f, a2 = 0.f, a3 = 0.f;
    float a4 = 0.f, a5 = 0.f, a6 = 0.f, a7 = 0.f;

#define GATH(s) (*(const uint4*)(T + (size_t)(s) * 64 + c8))
#define ACCQ(t0, t1, t2, t3)                                                  \
    do {                                                                      \
        a0 += (b2f_lo(t0.x) + b2f_lo(t1.x)) + (b2f_lo(t2.x) + b2f_lo(t3.x));  \
        a1 += (b2f_hi(t0.x) + b2f_hi(t1.x)) + (b2f_hi(t2.x) + b2f_hi(t3.x));  \
        a2 += (b2f_lo(t0.y) + b2f_lo(t1.y)) + (b2f_lo(t2.y) + b2f_lo(t3.y));  \
        a3 += (b2f_hi(t0.y) + b2f_hi(t1.y)) + (b2f_hi(t2.y) + b2f_hi(t3.y));  \
        a4 += (b2f_lo(t0.z) + b2f_lo(t1.z)) + (b2f_lo(t2.z) + b2f_lo(t3.z));  \
        a5 += (b2f_hi(t0.z) + b2f_hi(t1.z)) + (b2f_hi(t2.z) + b2f_hi(t3.z));  \
        a6 += (b2f_lo(t0.w) + b2f_lo(t1.w)) + (b2f_lo(t2.w) + b2f_lo(t3.w));  \
        a7 += (b2f_hi(t0.w) + b2f_hi(t1.w)) + (b2f_hi(t2.w) + b2f_hi(t3.w));  \
    } while (0)

    int e = e0;
    if (total <= IDX_LDS) {
        // ---- fast path: indices from LDS, depth-2 gather pipeline ----
        uint4 A0, A1, A2, A3, B0, B1, B2, B3;
        bool haveA = false, haveB = false;
        if (e + 4 <= e1) {
            int o = e - ebase;
            A0 = GATH(shIdx[o]);     A1 = GATH(shIdx[o + 1]);
            A2 = GATH(shIdx[o + 2]); A3 = GATH(shIdx[o + 3]);
            e += 4; haveA = true;
            if (e + 4 <= e1) {
                o = e - ebase;
                B0 = GATH(shIdx[o]);     B1 = GATH(shIdx[o + 1]);
                B2 = GATH(shIdx[o + 2]); B3 = GATH(shIdx[o + 3]);
                e += 4; haveB = true;
            }
        }
        while (haveA) {
            ACCQ(A0, A1, A2, A3);
            if (e + 4 <= e1) {
                int o = e - ebase;
                A0 = GATH(shIdx[o]);     A1 = GATH(shIdx[o + 1]);
                A2 = GATH(shIdx[o + 2]); A3 = GATH(shIdx[o + 3]);
                e += 4;
            } else haveA = false;
            if (!haveB) break;
            ACCQ(B0, B1, B2, B3);
            if (e + 4 <= e1) {
                int o = e - ebase;
                B0 = GATH(shIdx[o]);     B1 = GATH(shIdx[o + 1]);
                B2 = GATH(shIdx[o + 2]); B3 = GATH(shIdx[o + 3]);
                e += 4;
            } else haveB = false;
        }
        // tail 0..3 edges, batched single round trip
        const int rem = e1 - e;
        if (rem > 0) {
            int o = e - ebase;
            int s0 = shIdx[o];
            int s1 = (rem > 1) ? shIdx[o + 1] : s0;
            int s2 = (rem > 2) ? shIdx[o + 2] : s0;
            uint4 q0 = GATH(s0), q1 = GATH(s1), q2 = GATH(s2);
            a0 += b2f_lo(q0.x); a1 += b2f_hi(q0.x);
            a2 += b2f_lo(q0.y); a3 += b2f_hi(q0.y);
            a4 += b2f_lo(q0.z); a5 += b2f_hi(q0.z);
            a6 += b2f_lo(q0.w); a7 += b2f_hi(q0.w);
            if (rem > 1) {
                a0 += b2f_lo(q1.x); a1 += b2f_hi(q1.x);
                a2 += b2f_lo(q1.y); a3 += b2f_hi(q1.y);
                a4 += b2f_lo(q1.z); a5 += b2f_hi(q1.z);
                a6 += b2f_lo(q1.w); a7 += b2f_hi(q1.w);
            }
            if (rem > 2) {
                a0 += b2f_lo(q2.x); a1 += b2f_hi(q2.x);
                a2 += b2f_lo(q2.y); a3 += b2f_hi(q2.y);
                a4 += b2f_lo(q2.z); a5 += b2f_hi(q2.z);
                a6 += b2f_lo(q2.w); a7 += b2f_hi(q2.w);
            }
        }
    } else {
        // ---- overflow fallback (statistically unreachable): R15 loop ----
        uint4 t0, t1, t2, t3;
        bool have = (e + 4 <= e1);
        if (have) {
            int s0 = srcE[e], s1 = srcE[e + 1], s2 = srcE[e + 2], s3 = srcE[e + 3];
            t0 = GATH(s0); t1 = GATH(s1); t2 = GATH(s2); t3 = GATH(s3);
            e += 4;
        }
        while (have) {
            const bool next = (e + 4 <= e1);
            int s0, s1, s2, s3;
            if (next) { s0 = srcE[e]; s1 = srcE[e + 1]; s2 = srcE[e + 2]; s3 = srcE[e + 3]; }
            ACCQ(t0, t1, t2, t3);
            if (next) {
                t0 = GATH(s0); t1 = GATH(s1); t2 = GATH(s2); t3 = GATH(s3);
                e += 4;
            }
            have = next;
        }
        const int rem = e1 - e;
        if (rem > 0) {
            int s0 = srcE[e];
            int s1 = (rem > 1) ? srcE[e + 1] : s0;
            int s2 = (rem > 2) ? srcE[e + 2] : s0;
            uint4 q0 = GATH(s0), q1 = GATH(s1), q2 = GATH(s2);
            a0 += b2f_lo(q0.x); a1 += b2f_hi(q0.x);
            a2 += b2f_lo(q0.y); a3 += b2f_hi(q0.y);
            a4 += b2f_lo(q0.z); a5 += b2f_hi(q0.z);
            a6 += b2f_lo(q0.w); a7 += b2f_hi(q0.w);
            if (rem > 1) {
                a0 += b2f_lo(q1.x); a1 += b2f_hi(q1.x);
                a2 += b2f_lo(q1.y); a3 += b2f_hi(q1.y);
                a4 += b2f_lo(q1.z); a5 += b2f_hi(q1.z);
                a6 += b2f_lo(q1.w); a7 += b2f_hi(q1.w);
            }
            if (rem > 2) {
                a0 += b2f_lo(q2.x); a1 += b2f_hi(q2.x);
                a2 += b2f_lo(q2.y); a3 += b2f_hi(q2.y);
                a4 += b2f_lo(q2.z); a5 += b2f_hi(q2.z);
                a6 += b2f_lo(q2.w); a7 += b2f_hi(q2.w);
            }
        }
    }
#undef GATH
#undef ACCQ

    if constexpr (OUT_F32) {
        float* q = (float*)Hv + (size_t)node * 64 + c8;
        *(float4*)q       = make_float4(a0, a1, a2, a3);
        *(float4*)(q + 4) = make_float4(a4, a5, a6, a7);
    } else {
        ushort4 o0, o1;
        o0.x = f2b(a0); o0.y = f2b(a1); o0.z = f2b(a2); o0.w = f2b(a3);
        o1.x = f2b(a4); o1.y = f2b(a5); o1.z = f2b(a6); o1.w = f2b(a7);
        unsigned short* q = (unsigned short*)Hv + (size_t)node * 64 + c8;
        *(ushort4*)q       = o0;
        *(ushort4*)(q + 4) = o1;
    }
}

extern "C" void kernel_launch(void* const* d_in, const int* in_sizes, int n_in,
                              void* d_out, int out_size, void* d_ws, size_t ws_size,
                              hipStream_t stream) {
    const int*   src  = (const int*)d_in[0];
    const int*   dst  = (const int*)d_in[1];
    const float* feat = (const float*)d_in[2];
    const float* W1   = (const float*)d_in[3];
    const float* W2   = (const float*)d_in[4];
    const float* W3   = (const float*)d_in[5];
    float* out = (float*)d_out;

    // ws layout (bytes): T@0, H@5.25M, rowptr@10.5M, Wt123 after.
    char* wsb = (char*)d_ws;
    unsigned short* T     = (unsigned short*)wsb;
    unsigned short* H     = (unsigned short*)(wsb + (size_t)5505024);
    int* rowptr           = (int*)(wsb + (size_t)11010048);
    unsigned short* Wt123 = (unsigned short*)(wsb + (size_t)11010048 + 163968);

    const int scatterBlocks = (N_NODES + 31) / 32;   // 1250 (8 nodes x 4 waves)

    // out = S^3 . (X @ (W1 W2 W3))  — S = segment-sum, commutes with W
    prep<<<RP_BLOCKS + W_BLOCKS, 256, 0, stream>>>(dst, rowptr, W1, W2, W3, Wt123);
    gemm_mfma64<<<625, 256, 0, stream>>>(feat, Wt123, T);
    scatter8<false><<<scatterBlocks, 256, 0, stream>>>(T, src, rowptr, H);
    scatter8<false><<<scatterBlocks, 256, 0, stream>>>(H, src, rowptr, T);
    scatter8<true><<<scatterBlocks, 256, 0, stream>>>(T, src, rowptr, out);
}